// Round 1
// baseline (109.278 us; speedup 1.0000x reference)
//
#include <hip/hip_runtime.h>

// 1 sample per thread, scalar complex math. Rationale: v_pk_fma_f32 is
// throughput-neutral on gfx950 (157.3 TF spec == 1 FMA/lane/cycle, so packed
// must be 4-cycle issue) but packing forced 2-sample state = 64 VGPRs for
// st[] alone -> VGPR_Count=100 -> 4 waves/SIMD -> latency-bound (VALUBusy 48%).
// Unpacked state is 32 VGPRs; __launch_bounds__(256,8) targets <=64 VGPR ->
// 8 waves/SIMD for 2x latency hiding at identical total FLOPs.

struct C { float r, i; };

__device__ __forceinline__ C cmul(C a, C b) {
    C o;
    o.r = fmaf(a.r, b.r, -(a.i * b.i));
    o.i = fmaf(a.r, b.i,   a.i * b.r);
    return o;
}

// o = u*a + w*b where u=(ur,ui), w=(wr,wi) are wave-uniform gate entries.
__device__ __forceinline__ C cmadd(float ur, float ui, float wr, float wi, C a, C b) {
    C o;
    o.r = fmaf(ur, a.r, fmaf(-ui, a.i, fmaf(wr, b.r, -(wi * b.i))));
    o.i = fmaf(ur, a.i, fmaf( ui, a.r, fmaf(wr, b.i,   wi * b.r)));
    return o;
}

// Apply 2x2 complex gate (A4=[u00.re u00.im u01.re u01.im], B4=[u10 u11]) to bit BP.
template <int BP>
__device__ __forceinline__ void apply_gate(C st[16], float4 A4, float4 B4) {
#pragma unroll
    for (int i = 0; i < 8; i++) {
        const int lo = ((i >> BP) << (BP + 1)) | (i & ((1 << BP) - 1));
        const int hi = lo | (1 << BP);
        const C a = st[lo], b = st[hi];
        st[lo] = cmadd(A4.x, A4.y, A4.z, A4.w, a, b);
        st[hi] = cmadd(B4.x, B4.y, B4.z, B4.w, a, b);
    }
}

// CNOT: pure register permutation (free at full unroll).
template <int CB, int TB>
__device__ __forceinline__ void cnot(C st[16]) {
#pragma unroll
    for (int i = 0; i < 16; i++) {
        if ((i & (1 << CB)) && !(i & (1 << TB))) {
            C t = st[i];
            st[i] = st[i | (1 << TB)];
            st[i | (1 << TB)] = t;
        }
    }
}

struct Enc { float r0, i0, r1, i1; };
// v_q = (cos(xn) e^{-i xn/2}, sin(xn) e^{+i xn/2}), xn = pi*tanh(x).
// HW v_sin/v_cos take REVOLUTIONS: sin(pi t/2) = v_sin(t/4), t in (-1,1) -> no range reduction.
__device__ __forceinline__ Enc encode(float xq) {
    const float ax = fabsf(xq);
    const float e  = __builtin_amdgcn_exp2f(ax * -2.8853900817779268f);  // exp(-2|x|)
    const float r  = __builtin_amdgcn_rcpf(1.0f + e);
    const float t  = copysignf((1.0f - e) * r, xq);                       // tanh(x)
    const float sh = __builtin_amdgcn_sinf(t * 0.25f);                    // sin(pi t/2)
    const float ch = __builtin_amdgcn_cosf(t * 0.25f);                    // cos(pi t/2)
    const float s  = 2.0f * sh * ch;                                      // sin(pi t)
    const float c  = fmaf(-2.0f * sh, sh, 1.0f);                          // cos(pi t)
    return {c * ch, -(c * sh), s * ch, s * sh};
}

__global__ __launch_bounds__(256, 8) void qlayer_kernel(const float* __restrict__ x,
                                                        const float* __restrict__ qw,
                                                        float* __restrict__ out, int B) {
    __shared__ float4 Ug[12][2];
    const int tid = threadIdx.x;
    if (tid < 12) {
        const float phi = qw[tid * 3 + 0];
        const float th  = qw[tid * 3 + 1];
        const float om  = qw[tid * 3 + 2];
        // Rot = RZ(om) RY(th) RZ(phi)
        float s, c;   __sincosf(0.5f * th, &s, &c);
        float sa, ca; __sincosf(0.5f * (phi + om), &sa, &ca);
        float sb, cb; __sincosf(0.5f * (phi - om), &sb, &cb);
        Ug[tid][0] = make_float4(c * ca, -c * sa, -s * cb, -s * sb);
        Ug[tid][1] = make_float4(s * cb, -s * sb, c * ca, c * sa);
    }
    __syncthreads();

    const int b = blockIdx.x * 256 + tid;
    if (b >= B) return;

    const float4 xv = reinterpret_cast<const float4*>(x)[b];
    const float xs[4] = {xv.x, xv.y, xv.z, xv.w};

    // Encode + merge layer-0 Rot into the per-qubit 2-vectors (still product state).
    C v[4][2];
#pragma unroll
    for (int q = 0; q < 4; q++) {
        const Enc e = encode(xs[q]);
        const C a{e.r0, e.i0}, bv{e.r1, e.i1};
        const float4 A4 = Ug[q][0], B4 = Ug[q][1];
        v[q][0] = cmadd(A4.x, A4.y, A4.z, A4.w, a, bv);
        v[q][1] = cmadd(B4.x, B4.y, B4.z, B4.w, a, bv);
    }

    // Outer product: st[(i01<<2)|i23] = t01[i01] * t23[i23]
    C t01[4], t23[4];
#pragma unroll
    for (int i = 0; i < 4; i++) {
        t01[i] = cmul(v[0][(i >> 1) & 1], v[1][i & 1]);
        t23[i] = cmul(v[2][(i >> 1) & 1], v[3][i & 1]);
    }
    C st[16];
#pragma unroll
    for (int i = 0; i < 16; i++) st[i] = cmul(t01[i >> 2], t23[i & 3]);

    // Layer-0 CNOT ring (qubit q -> bit 3-q).
    cnot<3, 2>(st); cnot<2, 1>(st); cnot<1, 0>(st); cnot<0, 3>(st);

    // Layer 1
    apply_gate<3>(st, Ug[4][0], Ug[4][1]);
    apply_gate<2>(st, Ug[5][0], Ug[5][1]);
    apply_gate<1>(st, Ug[6][0], Ug[6][1]);
    apply_gate<0>(st, Ug[7][0], Ug[7][1]);
    cnot<3, 2>(st); cnot<2, 1>(st); cnot<1, 0>(st); cnot<0, 3>(st);
    // Layer 2
    apply_gate<3>(st, Ug[8][0], Ug[8][1]);
    apply_gate<2>(st, Ug[9][0], Ug[9][1]);
    apply_gate<1>(st, Ug[10][0], Ug[10][1]);
    apply_gate<0>(st, Ug[11][0], Ug[11][1]);
    cnot<3, 2>(st); cnot<2, 1>(st); cnot<1, 0>(st); cnot<0, 3>(st);

    // Readout: normalized state => <Z_q> = 1 - 2*sum_{bit(3-q)=1} |amp|^2.
    float p[16];
#pragma unroll
    for (int i = 0; i < 16; i++) p[i] = fmaf(st[i].r, st[i].r, st[i].i * st[i].i);

    float pr[8];
#pragma unroll
    for (int j = 0; j < 8; j++) pr[j] = p[2 * j] + p[2 * j + 1];

    const float s3 = (pr[4] + pr[5]) + (pr[6] + pr[7]);
    const float s2 = (pr[2] + pr[3]) + (pr[6] + pr[7]);
    const float s1 = (pr[1] + pr[3]) + (pr[5] + pr[7]);
    const float s0 = ((p[1] + p[3]) + (p[5] + p[7])) + ((p[9] + p[11]) + (p[13] + p[15]));

    float4 ev;
    ev.x = fmaf(-2.0f, s3, 1.0f);
    ev.y = fmaf(-2.0f, s2, 1.0f);
    ev.z = fmaf(-2.0f, s1, 1.0f);
    ev.w = fmaf(-2.0f, s0, 1.0f);
    reinterpret_cast<float4*>(out)[b] = ev;
}

extern "C" void kernel_launch(void* const* d_in, const int* in_sizes, int n_in,
                              void* d_out, int out_size, void* d_ws, size_t ws_size,
                              hipStream_t stream) {
    const float* x  = (const float*)d_in[0];
    const float* qw = (const float*)d_in[1];
    float* out = (float*)d_out;
    const int B = in_sizes[0] / 4;
    const int blocks = (B + 255) / 256;   // 1 sample per thread
    qlayer_kernel<<<blocks, 256, 0, stream>>>(x, qw, out, B);
}

// Round 2
// 97.634 us; speedup vs baseline: 1.1193x; 1.1193x over previous
//
#include <hip/hip_runtime.h>

// 1 sample per thread, scalar complex math.
// Round-1 post-mortem: __launch_bounds__(256,8) (64-VGPR cap) forced the
// allocator to spill st[16] to scratch -> WRITE_SIZE 16->117 MB, FETCH 8->55 MB,
// dispatch stuck at 52us. True live set at the outer-product is ~70-80 VGPRs.
// Fix: (256,6) -> 85-VGPR cap, zero spill, 6 waves/SIMD (75% occupancy).
// Readout fused into 4 accumulators to trim tail register pressure.

struct C { float r, i; };

__device__ __forceinline__ C cmul(C a, C b) {
    C o;
    o.r = fmaf(a.r, b.r, -(a.i * b.i));
    o.i = fmaf(a.r, b.i,   a.i * b.r);
    return o;
}

// o = u*a + w*b where u=(ur,ui), w=(wr,wi) are wave-uniform gate entries.
__device__ __forceinline__ C cmadd(float ur, float ui, float wr, float wi, C a, C b) {
    C o;
    o.r = fmaf(ur, a.r, fmaf(-ui, a.i, fmaf(wr, b.r, -(wi * b.i))));
    o.i = fmaf(ur, a.i, fmaf( ui, a.r, fmaf(wr, b.i,   wi * b.r)));
    return o;
}

// Apply 2x2 complex gate (A4=[u00.re u00.im u01.re u01.im], B4=[u10 u11]) to bit BP.
template <int BP>
__device__ __forceinline__ void apply_gate(C st[16], float4 A4, float4 B4) {
#pragma unroll
    for (int i = 0; i < 8; i++) {
        const int lo = ((i >> BP) << (BP + 1)) | (i & ((1 << BP) - 1));
        const int hi = lo | (1 << BP);
        const C a = st[lo], b = st[hi];
        st[lo] = cmadd(A4.x, A4.y, A4.z, A4.w, a, b);
        st[hi] = cmadd(B4.x, B4.y, B4.z, B4.w, a, b);
    }
}

// CNOT: pure register permutation (free at full unroll).
template <int CB, int TB>
__device__ __forceinline__ void cnot(C st[16]) {
#pragma unroll
    for (int i = 0; i < 16; i++) {
        if ((i & (1 << CB)) && !(i & (1 << TB))) {
            C t = st[i];
            st[i] = st[i | (1 << TB)];
            st[i | (1 << TB)] = t;
        }
    }
}

struct Enc { float r0, i0, r1, i1; };
// v_q = (cos(xn) e^{-i xn/2}, sin(xn) e^{+i xn/2}), xn = pi*tanh(x).
// HW v_sin/v_cos take REVOLUTIONS: sin(pi t/2) = v_sin(t/4), t in (-1,1) -> no range reduction.
__device__ __forceinline__ Enc encode(float xq) {
    const float ax = fabsf(xq);
    const float e  = __builtin_amdgcn_exp2f(ax * -2.8853900817779268f);  // exp(-2|x|)
    const float r  = __builtin_amdgcn_rcpf(1.0f + e);
    const float t  = copysignf((1.0f - e) * r, xq);                       // tanh(x)
    const float sh = __builtin_amdgcn_sinf(t * 0.25f);                    // sin(pi t/2)
    const float ch = __builtin_amdgcn_cosf(t * 0.25f);                    // cos(pi t/2)
    const float s  = 2.0f * sh * ch;                                      // sin(pi t)
    const float c  = fmaf(-2.0f * sh, sh, 1.0f);                          // cos(pi t)
    return {c * ch, -(c * sh), s * ch, s * sh};
}

__global__ __launch_bounds__(256, 6) void qlayer_kernel(const float* __restrict__ x,
                                                        const float* __restrict__ qw,
                                                        float* __restrict__ out, int B) {
    __shared__ float4 Ug[12][2];
    const int tid = threadIdx.x;
    if (tid < 12) {
        const float phi = qw[tid * 3 + 0];
        const float th  = qw[tid * 3 + 1];
        const float om  = qw[tid * 3 + 2];
        // Rot = RZ(om) RY(th) RZ(phi)
        float s, c;   __sincosf(0.5f * th, &s, &c);
        float sa, ca; __sincosf(0.5f * (phi + om), &sa, &ca);
        float sb, cb; __sincosf(0.5f * (phi - om), &sb, &cb);
        Ug[tid][0] = make_float4(c * ca, -c * sa, -s * cb, -s * sb);
        Ug[tid][1] = make_float4(s * cb, -s * sb, c * ca, c * sa);
    }
    __syncthreads();

    const int b = blockIdx.x * 256 + tid;
    if (b >= B) return;

    const float4 xv = reinterpret_cast<const float4*>(x)[b];
    const float xs[4] = {xv.x, xv.y, xv.z, xv.w};

    // Encode + merge layer-0 Rot into the per-qubit 2-vectors (still product state).
    C v[4][2];
#pragma unroll
    for (int q = 0; q < 4; q++) {
        const Enc e = encode(xs[q]);
        const C a{e.r0, e.i0}, bv{e.r1, e.i1};
        const float4 A4 = Ug[q][0], B4 = Ug[q][1];
        v[q][0] = cmadd(A4.x, A4.y, A4.z, A4.w, a, bv);
        v[q][1] = cmadd(B4.x, B4.y, B4.z, B4.w, a, bv);
    }

    // Outer product: st[(i01<<2)|i23] = t01[i01] * t23[i23]
    C t01[4], t23[4];
#pragma unroll
    for (int i = 0; i < 4; i++) {
        t01[i] = cmul(v[0][(i >> 1) & 1], v[1][i & 1]);
        t23[i] = cmul(v[2][(i >> 1) & 1], v[3][i & 1]);
    }
    C st[16];
#pragma unroll
    for (int i = 0; i < 16; i++) st[i] = cmul(t01[i >> 2], t23[i & 3]);

    // Layer-0 CNOT ring (qubit q -> bit 3-q).
    cnot<3, 2>(st); cnot<2, 1>(st); cnot<1, 0>(st); cnot<0, 3>(st);

    // Layer 1
    apply_gate<3>(st, Ug[4][0], Ug[4][1]);
    apply_gate<2>(st, Ug[5][0], Ug[5][1]);
    apply_gate<1>(st, Ug[6][0], Ug[6][1]);
    apply_gate<0>(st, Ug[7][0], Ug[7][1]);
    cnot<3, 2>(st); cnot<2, 1>(st); cnot<1, 0>(st); cnot<0, 3>(st);
    // Layer 2
    apply_gate<3>(st, Ug[8][0], Ug[8][1]);
    apply_gate<2>(st, Ug[9][0], Ug[9][1]);
    apply_gate<1>(st, Ug[10][0], Ug[10][1]);
    apply_gate<0>(st, Ug[11][0], Ug[11][1]);
    cnot<3, 2>(st); cnot<2, 1>(st); cnot<1, 0>(st); cnot<0, 3>(st);

    // Readout: normalized state => <Z_q> = 1 - 2*sum_{bit(3-q)=1} |amp|^2.
    // Fused: accumulate the 4 marginals directly (no p[16]/pr[8] arrays).
    float s0 = 0.f, s1 = 0.f, s2 = 0.f, s3 = 0.f;
#pragma unroll
    for (int i = 0; i < 16; i++) {
        const float p = fmaf(st[i].r, st[i].r, st[i].i * st[i].i);
        if (i & 8) s3 += p;
        if (i & 4) s2 += p;
        if (i & 2) s1 += p;
        if (i & 1) s0 += p;
    }

    float4 ev;
    ev.x = fmaf(-2.0f, s3, 1.0f);
    ev.y = fmaf(-2.0f, s2, 1.0f);
    ev.z = fmaf(-2.0f, s1, 1.0f);
    ev.w = fmaf(-2.0f, s0, 1.0f);
    reinterpret_cast<float4*>(out)[b] = ev;
}

extern "C" void kernel_launch(void* const* d_in, const int* in_sizes, int n_in,
                              void* d_out, int out_size, void* d_ws, size_t ws_size,
                              hipStream_t stream) {
    const float* x  = (const float*)d_in[0];
    const float* qw = (const float*)d_in[1];
    float* out = (float*)d_out;
    const int B = in_sizes[0] / 4;
    const int blocks = (B + 255) / 256;   // 1 sample per thread
    qlayer_kernel<<<blocks, 256, 0, stream>>>(x, qw, out, B);
}